// Round 6
// baseline (5383.061 us; speedup 1.0000x reference)
//
#include <hip/hip_runtime.h>
#include <stdint.h>
#include <math.h>

#define NV 8192
#define EMB 512
#define CLS 257
#define DEG 32
#define TV 8
#define RSTRIDE 260   // padded row stride in floats (1040 B, 16B-aligned)

// ---------------------------------------------------------------------------
// Threefry-2x32, 20 rounds — exactly JAX's _threefry2x32. constexpr so the
// input-independent key chain (seed 42) can be baked in at compile time.
// ---------------------------------------------------------------------------
struct KP { uint32_t a, b; };

__host__ __device__ constexpr KP tfc(uint32_t k0, uint32_t k1,
                                     uint32_t x0, uint32_t x1) {
  const uint32_t ks2 = k0 ^ k1 ^ 0x1BD11BDAu;
  uint32_t v0 = x0 + k0, v1 = x1 + k1;
#define QR(r) { v0 += v1; v1 = (v1 << (r)) | (v1 >> (32 - (r))); v1 ^= v0; }
  QR(13) QR(15) QR(26) QR(6)
  v0 += k1;  v1 += ks2 + 1u;
  QR(17) QR(29) QR(16) QR(24)
  v0 += ks2; v1 += k0 + 2u;
  QR(13) QR(15) QR(26) QR(6)
  v0 += k0;  v1 += k1 + 3u;
  QR(17) QR(29) QR(16) QR(24)
  v0 += k1;  v1 += ks2 + 4u;
  QR(13) QR(15) QR(26) QR(6)
  v0 += ks2; v1 += k0 + 5u;
#undef QR
  return KP{v0, v1};
}

struct Seg { KP e[256]; };
constexpr Seg mkseg(KP s) {
  Seg g{};
  g.e[0] = s;
  for (int i = 1; i < 256; ++i) g.e[i] = tfc(g.e[i - 1].a, g.e[i - 1].b, 0u, 0u);
  return g;
}
#define NXTSEG(prev) mkseg(tfc(prev.e[255].a, prev.e[255].b, 0u, 0u))
constexpr Seg SG0 = mkseg(KP{0u, 42u});
constexpr Seg SG1 = NXTSEG(SG0);   constexpr Seg SG2 = NXTSEG(SG1);
constexpr Seg SG3 = NXTSEG(SG2);   constexpr Seg SG4 = NXTSEG(SG3);
constexpr Seg SG5 = NXTSEG(SG4);   constexpr Seg SG6 = NXTSEG(SG5);
constexpr Seg SG7 = NXTSEG(SG6);   constexpr Seg SG8 = NXTSEG(SG7);
constexpr Seg SG9 = NXTSEG(SG8);   constexpr Seg SG10 = NXTSEG(SG9);
constexpr Seg SG11 = NXTSEG(SG10); constexpr Seg SG12 = NXTSEG(SG11);
constexpr Seg SG13 = NXTSEG(SG12); constexpr Seg SG14 = NXTSEG(SG13);
constexpr Seg SG15 = NXTSEG(SG14); constexpr Seg SG16 = NXTSEG(SG15);
constexpr Seg SG17 = NXTSEG(SG16); constexpr Seg SG18 = NXTSEG(SG17);
constexpr Seg SG19 = NXTSEG(SG18); constexpr Seg SG20 = NXTSEG(SG19);
constexpr Seg SG21 = NXTSEG(SG20); constexpr Seg SG22 = NXTSEG(SG21);
constexpr Seg SG23 = NXTSEG(SG22); constexpr Seg SG24 = NXTSEG(SG23);
constexpr Seg SG25 = NXTSEG(SG24); constexpr Seg SG26 = NXTSEG(SG25);
constexpr Seg SG27 = NXTSEG(SG26); constexpr Seg SG28 = NXTSEG(SG27);
constexpr Seg SG29 = NXTSEG(SG28); constexpr Seg SG30 = NXTSEG(SG29);
constexpr Seg SG31 = NXTSEG(SG30);

struct KT { uint32_t hi[8192]; uint32_t lo[8192]; };
constexpr KT mkkt() {
  KT t{};
  const Seg* sg[32] = {
    &SG0,  &SG1,  &SG2,  &SG3,  &SG4,  &SG5,  &SG6,  &SG7,
    &SG8,  &SG9,  &SG10, &SG11, &SG12, &SG13, &SG14, &SG15,
    &SG16, &SG17, &SG18, &SG19, &SG20, &SG21, &SG22, &SG23,
    &SG24, &SG25, &SG26, &SG27, &SG28, &SG29, &SG30, &SG31 };
  for (int s = 0; s < 32; ++s)
    for (int i = 0; i < 256; ++i) {
      const int v = 1 + s * 256 + i;
      if (v < 8192) { t.hi[v] = sg[s]->e[i].a; t.lo[v] = sg[s]->e[i].b; }
    }
  return t;
}
__device__ const KT KEYS = mkkt();

// ---------------------------------------------------------------------------
// K1: graph_emb = mean(embeddings, axis=0)
// ---------------------------------------------------------------------------
__global__ __launch_bounds__(256) void colmean_part(const float* __restrict__ emb,
                                                    float* __restrict__ part) {
  const int b = blockIdx.x;
  const int t = threadIdx.x;
  for (int j = t; j < EMB; j += 256) {
    float s = 0.f;
    const int r0 = b * 128;
    for (int r = 0; r < 128; ++r) s += emb[(size_t)(r0 + r) * EMB + j];
    part[(size_t)b * EMB + j] = s;
  }
}

__global__ __launch_bounds__(256) void colmean_fin(const float* __restrict__ part,
                                                   float* __restrict__ g) {
  const int t = threadIdx.x;
  for (int j = t; j < EMB; j += 256) {
    float s = 0.f;
    for (int b = 0; b < 64; ++b) s += part[(size_t)b * EMB + j];
    g[j] = s / 8192.0f;
  }
}

// ---------------------------------------------------------------------------
// K2: fused 3-layer MLP, TV=8 (bit-identical per-vertex math to round-5's
// TV=16 version: same k-order, same fmaf sequence) + epilogue:
// pl[] = li + gumbel, er[] = exp(li - rowmax).
// ---------------------------------------------------------------------------
__global__ __launch_bounds__(256) void mlp3h(
    const float* __restrict__ emb, const float* __restrict__ g,
    const float* __restrict__ W1, const float* __restrict__ b1,
    const float* __restrict__ W2, const float* __restrict__ b2,
    const float* __restrict__ W3, const float* __restrict__ b3,
    float* __restrict__ pl, float* __restrict__ er)
{
  __shared__ float xs[TV][68];
  __shared__ float gs[EMB];
  __shared__ float h1s[TV][EMB];     // 16 KB
  __shared__ float h2s[TV][400];     // 12.8 KB
  __shared__ float redw[TV][4];
  __shared__ float li256s[TV];
  __shared__ float mrs[TV];

  const int t  = threadIdx.x;
  const int tx = t & 63;
  const int ty = t >> 6;
  const int v0 = blockIdx.x * TV;

  for (int j = t; j < EMB; j += 256) gs[j] = g[j];

  float acc[2][8];
#pragma unroll
  for (int a = 0; a < 2; ++a)
#pragma unroll
    for (int b = 0; b < 8; ++b) acc[a][b] = 0.f;

  for (int kc = 0; kc < 8; ++kc) {
    __syncthreads();
    if (t < 128) {
      const int vv = t >> 4;
      const int kk = (t & 15) << 2;
      const float4 s4 = *reinterpret_cast<const float4*>(
          &emb[(size_t)(v0 + vv) * EMB + kc * 64 + kk]);
      xs[vv][kk] = s4.x; xs[vv][kk + 1] = s4.y;
      xs[vv][kk + 2] = s4.z; xs[vv][kk + 3] = s4.w;
    }
    __syncthreads();
    float cacc[2][8];
#pragma unroll
    for (int a = 0; a < 2; ++a)
#pragma unroll
      for (int b = 0; b < 8; ++b) cacc[a][b] = 0.f;
    for (int kk = 0; kk < 64; ++kk) {
      const int k = kc * 64 + kk;
      float w[8];
#pragma unroll
      for (int jj = 0; jj < 8; ++jj) w[jj] = W1[(size_t)k * EMB + tx + 64 * jj];
      float xv[2];
#pragma unroll
      for (int vv = 0; vv < 2; ++vv) xv[vv] = xs[ty * 2 + vv][kk];
#pragma unroll
      for (int vv = 0; vv < 2; ++vv)
#pragma unroll
        for (int jj = 0; jj < 8; ++jj)
          cacc[vv][jj] = fmaf(xv[vv], w[jj], cacc[vv][jj]);
    }
#pragma unroll
    for (int a = 0; a < 2; ++a)
#pragma unroll
      for (int b = 0; b < 8; ++b) acc[a][b] += cacc[a][b];
  }

  float gacc[8];
#pragma unroll
  for (int b = 0; b < 8; ++b) gacc[b] = 0.f;
  for (int kc = 0; kc < 8; ++kc) {
    float cg[8];
#pragma unroll
    for (int b = 0; b < 8; ++b) cg[b] = 0.f;
    for (int kk = 0; kk < 64; ++kk) {
      const int k = kc * 64 + kk;
      const float gv = gs[k];
#pragma unroll
      for (int jj = 0; jj < 8; ++jj)
        cg[jj] = fmaf(gv, W1[(size_t)(EMB + k) * EMB + tx + 64 * jj], cg[jj]);
    }
#pragma unroll
    for (int b = 0; b < 8; ++b) gacc[b] += cg[b];
  }

#pragma unroll
  for (int jj = 0; jj < 8; ++jj) {
    const int j = tx + 64 * jj;
    const float bj = b1[j];
#pragma unroll
    for (int vv = 0; vv < 2; ++vv) {
      float h = (acc[vv][jj] + gacc[jj]) + bj;
      h = (h >= 0.f) ? h : 0.01f * h;
      h1s[ty * 2 + vv][j] = h;
    }
  }
  __syncthreads();

  const int j2a = t;
  const int j2b = t + 256;
  float a2[TV], a2b[TV];
#pragma unroll
  for (int vv = 0; vv < TV; ++vv) { a2[vv] = 0.f; a2b[vv] = 0.f; }
  for (int kc = 0; kc < 8; ++kc) {
    float c2[TV], c2b[TV];
#pragma unroll
    for (int vv = 0; vv < TV; ++vv) { c2[vv] = 0.f; c2b[vv] = 0.f; }
    for (int kk = 0; kk < 64; ++kk) {
      const int k = kc * 64 + kk;
      const float w0  = W2[(size_t)k * 400 + j2a];
      const float w1v = (j2b < 400) ? W2[(size_t)k * 400 + j2b] : 0.f;
#pragma unroll
      for (int vv = 0; vv < TV; ++vv) {
        const float hv = h1s[vv][k];
        c2[vv]  = fmaf(hv, w0,  c2[vv]);
        c2b[vv] = fmaf(hv, w1v, c2b[vv]);
      }
    }
#pragma unroll
    for (int vv = 0; vv < TV; ++vv) { a2[vv] += c2[vv]; a2b[vv] += c2b[vv]; }
  }
  {
    const float bja = b2[j2a];
#pragma unroll
    for (int vv = 0; vv < TV; ++vv) {
      float h = a2[vv] + bja;
      h2s[vv][j2a] = (h >= 0.f) ? h : 0.01f * h;
    }
    if (j2b < 400) {
      const float bjb = b2[j2b];
#pragma unroll
      for (int vv = 0; vv < TV; ++vv) {
        float h = a2b[vv] + bjb;
        h2s[vv][j2b] = (h >= 0.f) ? h : 0.01f * h;
      }
    }
  }
  __syncthreads();

  float a3[TV], a3x[TV];
#pragma unroll
  for (int vv = 0; vv < TV; ++vv) { a3[vv] = 0.f; a3x[vv] = 0.f; }
  for (int kc = 0; kc < 8; ++kc) {
    float c3[TV], c3x[TV];
#pragma unroll
    for (int vv = 0; vv < TV; ++vv) { c3[vv] = 0.f; c3x[vv] = 0.f; }
    for (int kk = 0; kk < 50; ++kk) {
      const int k = kc * 50 + kk;
      const float w0 = W3[(size_t)k * CLS + t];
      const float wx = (t == 0) ? W3[(size_t)k * CLS + 256] : 0.f;
#pragma unroll
      for (int vv = 0; vv < TV; ++vv) {
        const float hv = h2s[vv][k];
        c3[vv]  = fmaf(hv, w0, c3[vv]);
        c3x[vv] = fmaf(hv, wx, c3x[vv]);
      }
    }
#pragma unroll
    for (int vv = 0; vv < TV; ++vv) { a3[vv] += c3[vv]; a3x[vv] += c3x[vv]; }
  }

  const float bj = b3[t];
  float li_[TV];
#pragma unroll
  for (int vv = 0; vv < TV; ++vv) li_[vv] = a3[vv] + bj;

#pragma unroll
  for (int vv = 0; vv < TV; ++vv) {
    float m = li_[vv];
#pragma unroll
    for (int off = 1; off < 64; off <<= 1) m = fmaxf(m, __shfl_xor(m, off));
    if ((t & 63) == 0) redw[vv][t >> 6] = m;
  }
  if (t == 0) {
    const float bx = b3[256];
#pragma unroll
    for (int vv = 0; vv < TV; ++vv) li256s[vv] = a3x[vv] + bx;
  }
  __syncthreads();
  if (t < TV) {
    const float m = fmaxf(fmaxf(redw[t][0], redw[t][1]),
                          fmaxf(redw[t][2], redw[t][3]));
    mrs[t] = fmaxf(m, li256s[t]);
  }
  __syncthreads();

#pragma unroll
  for (int vv = 0; vv < TV; ++vv) {
    const int v = v0 + vv;
    const float li = li_[vv];
    const KP sk = tfc(KEYS.hi[v], KEYS.lo[v], 0u, 1u);
    const KP o  = tfc(sk.a, sk.b, 0u, (uint32_t)t);
    const uint32_t bb = o.a ^ o.b;
    const float f = __uint_as_float(0x3f800000u | (bb >> 9)) - 1.0f;
    const float u = fmaxf(1.17549435e-38f, f);
    const float gg = -logf(-logf(u));
    pl[(size_t)v * RSTRIDE + t] = li + gg;
    er[(size_t)v * RSTRIDE + t] = expf(li - mrs[vv]);
  }
  if (t == 0) {
    const float bx = b3[256];
#pragma unroll
    for (int vv = 0; vv < TV; ++vv) {
      const int v = v0 + vv;
      const float li = a3x[vv] + bx;
      const KP sk = tfc(KEYS.hi[v], KEYS.lo[v], 0u, 1u);
      const KP o  = tfc(sk.a, sk.b, 0u, 256u);
      const uint32_t bb = o.a ^ o.b;
      const float f = __uint_as_float(0x3f800000u | (bb >> 9)) - 1.0f;
      const float u = fmaxf(1.17549435e-38f, f);
      const float gg = -logf(-logf(u));
      pl[(size_t)v * RSTRIDE + 256] = li + gg;
      er[(size_t)v * RSTRIDE + 256] = expf(li - mrs[vv]);
    }
  }
}

// ---------------------------------------------------------------------------
// helpers
// ---------------------------------------------------------------------------
#define DPPF(CTRL, OLDI, X) \
  __builtin_amdgcn_update_dpp((int)(OLDI), (X), (CTRL), 0xF, 0xF, false)
#define SRED(CTRL) { S += __int_as_float(DPPF(CTRL, 0, __float_as_int(S))); }

__device__ __forceinline__ uint32_t ordmap(float f) {
  const uint32_t s = __float_as_uint(f);
  return s ^ (0x80000000u | (uint32_t)((int32_t)s >> 31));
}

#define WG_SCOPE __HIP_MEMORY_SCOPE_WORKGROUP

// ---------------------------------------------------------------------------
// K2b: per-row descending sort of 257 perturbed logits by (ordmap(pl), ~idx).
// First 320 u16 of each pl row overwritten IN PLACE with sorted class ids.
// ---------------------------------------------------------------------------
__global__ __launch_bounds__(256) void sortrows(float* __restrict__ plbuf) {
  __shared__ uint64_t keys[4][512];
  const int t = threadIdx.x;
  const int w = t >> 6;
  const int lane = t & 63;
  const int v = blockIdx.x * 4 + w;
  const float* row = plbuf + (size_t)v * RSTRIDE;

#pragma unroll
  for (int j = 0; j < 8; ++j) {
    const int i = lane + 64 * j;
    uint32_t om = 0u;
    if (i < CLS) om = ordmap(row[i]);
    keys[w][i] = ((uint64_t)om << 9) | (uint64_t)(511 - i);
  }
  __syncthreads();

  for (int k = 2; k <= 512; k <<= 1) {
    for (int j = k >> 1; j > 0; j >>= 1) {
#pragma unroll
      for (int m = 0; m < 4; ++m) {
        const int p  = lane + 64 * m;
        const int i  = ((p & ~(j - 1)) << 1) | (p & (j - 1));
        const int ix = i | j;
        const uint64_t a = keys[w][i], b = keys[w][ix];
        const bool sw = ((i & k) == 0) ? (a < b) : (a > b);
        if (sw) { keys[w][i] = b; keys[w][ix] = a; }
      }
      __syncthreads();
    }
  }

  uint16_t* o16 = reinterpret_cast<uint16_t*>(plbuf) + (size_t)v * (RSTRIDE * 2);
#pragma unroll
  for (int j = 0; j < 5; ++j) {
    const int i = lane + 64 * j;
    if (i < 320) o16[i] = (uint16_t)(511u - (uint32_t)(keys[w][i] & 511u));
  }
}

// ---------------------------------------------------------------------------
// K3: producer-consumer scan, 3-stage pipelined consumer:
//   per iter v: [critical v] -> [maskbuild row v+2] -> [candload row v+3].
// Two named register sets (A = odd rows, B = even rows); loop unrolled x2.
// ---------------------------------------------------------------------------
#define HALF_STEP(V, CC, CB, CH, PN, QC, QN, DO_SYNC)                          \
  {                                                                            \
    const int v_ = (V);                                                        \
    if (DO_SYNC && ((v_ & 7) == 7)) {                                          \
      if (lane == 0)                                                           \
        __hip_atomic_store(&cons_done, (v_ + 1) >> 3, __ATOMIC_RELEASE,        \
                           WG_SCOPE);                                          \
      int tgt = ((v_ + 1) >> 3) + 2;                                           \
      if (tgt > 1024) tgt = 1024;                                              \
      while (__hip_atomic_load(&prod_done, __ATOMIC_ACQUIRE, WG_SCOPE) < tgt) {} \
    }                                                                          \
    /* ---- critical phase for v ---- */                                       \
    const int nu_ = n_used, fx_ = chosen_prev;                                 \
    bool al0 = (!((CB[0] >> (CC[0] & 31)) & 1u)) &&                            \
               (CC[0] < nu_ || CC[0] == 256) && !(CH && CC[0] == fx_);         \
    bool al1 = (!((CB[1] >> (CC[1] & 31)) & 1u)) &&                            \
               (CC[1] < nu_ || CC[1] == 256) && !(CH && CC[1] == fx_);         \
    bool al2 = (!((CB[2] >> (CC[2] & 31)) & 1u)) &&                            \
               (CC[2] < nu_ || CC[2] == 256) && !(CH && CC[2] == fx_);         \
    bool al3 = (!((CB[3] >> (CC[3] & 31)) & 1u)) &&                            \
               (CC[3] < nu_ || CC[3] == 256) && !(CH && CC[3] == fx_);         \
    bool al4 = (!((CB[4] >> (CC[4] & 31)) & 1u)) &&                            \
               (CC[4] < nu_ || CC[4] == 256) && !(CH && CC[4] == fx_);         \
    int raw = 256;                                                             \
    {                                                                          \
      uint64_t b_ = __ballot(al0);                                             \
      if (b_) raw = __builtin_amdgcn_readlane(CC[0], (int)__builtin_ctzll(b_));\
      else if ((b_ = __ballot(al1)))                                           \
        raw = __builtin_amdgcn_readlane(CC[1], (int)__builtin_ctzll(b_));      \
      else if ((b_ = __ballot(al2)))                                           \
        raw = __builtin_amdgcn_readlane(CC[2], (int)__builtin_ctzll(b_));      \
      else if ((b_ = __ballot(al3)))                                           \
        raw = __builtin_amdgcn_readlane(CC[3], (int)__builtin_ctzll(b_));      \
      else if ((b_ = __ballot(al4)))                                           \
        raw = __builtin_amdgcn_readlane(CC[4], (int)__builtin_ctzll(b_));      \
    }                                                                          \
    const bool isnew_ = (raw == 256);                                          \
    const int chosen_ = isnew_ ? nu_ : raw;                                    \
    if (isnew_) ++n_used;                                                      \
    if (lane == 0) {                                                           \
      colors[v_] = chosen_;                                                    \
      rawnu[v_] = (unsigned)raw | ((unsigned)nu_ << 16);                       \
    }                                                                          \
    chosen_prev = chosen_;                                                     \
    /* ---- maskbuild row v+2 (into CC/CB/CH; misses only colors[v+1]) ---- */ \
    {                                                                          \
      bbuf[v_ & 1][lane & 15] = 0u;                                            \
      CH = (__ballot(PN == v_ + 1) != 0ULL);                                   \
      const int cg_ = colors[PN];                                              \
      if (cg_ >= 0) atomicOr(&bbuf[v_ & 1][cg_ >> 5], 1u << (cg_ & 31));       \
      _Pragma("unroll")                                                        \
      for (int j = 0; j < 5; ++j) {                                            \
        CC[j] = PC_##CC[j];                                                    \
        CB[j] = bbuf[v_ & 1][CC[j] >> 5];                                      \
      }                                                                        \
    }                                                                          \
    /* ---- candload row v+3 into other-parity pending ---- */                 \
    {                                                                          \
      const int r3_ = (v_ + 3 < NV) ? v_ + 3 : NV - 1;                         \
      const int sB_ = (r3_ & 31) * 320;                                        \
      _Pragma("unroll")                                                        \
      for (int j = 0; j < 5; ++j) QC[j] = scR16[sB_ + 64 * j + lane];          \
      QN = nbrRing[(((r3_ >> 3) & 3) << 8) + ((r3_ & 7) << 5) + ln32];         \
    }                                                                          \
  }

__global__ __launch_bounds__(128) void scan6(
    const int* __restrict__ nbrG, const uint32_t* __restrict__ scG,
    unsigned* __restrict__ rawnu, float* __restrict__ out)
{
  __shared__ int colors[NV];            // 32 KB
  __shared__ uint32_t scR[32][160];     // 20 KB ring: 320 u16 cands/row
  __shared__ int nbrRing[1024];         // 4 KB: 4 chunks x 8 rows x 32
  __shared__ unsigned bbuf[2][16];
  __shared__ int prod_done, cons_done;

  const int t = threadIdx.x;
  const int lane = t & 63;
  const int ln32 = lane & 31;
  const uint16_t* scR16 = reinterpret_cast<const uint16_t*>(&scR[0][0]);

  for (int i = t; i < NV; i += 128) colors[i] = -1;
  if (t == 0) { colors[0] = 0; prod_done = 0; cons_done = 0; }
  __syncthreads();

  if (t >= 64) {
    // ================= producer wave =================
    for (int pc = 0; pc < 1024; ++pc) {
      while (__hip_atomic_load(&cons_done, __ATOMIC_ACQUIRE, WG_SCOPE) < pc - 3)
        __builtin_amdgcn_s_sleep(1);
      uint32_t x[8], y[8], z[8];
#pragma unroll
      for (int r = 0; r < 8; ++r) {
        const size_t base = (size_t)(pc * 8 + r) * RSTRIDE;   // u32 units
        x[r] = scG[base + lane];
        y[r] = scG[base + 64 + lane];
        z[r] = (lane < 32) ? scG[base + 128 + lane] : 0u;
      }
      const int4 nb4 = *reinterpret_cast<const int4*>(nbrG + pc * 256 + 4 * lane);
#pragma unroll
      for (int r = 0; r < 8; ++r) {
        const int slot = (pc * 8 + r) & 31;
        scR[slot][lane] = x[r];
        scR[slot][64 + lane] = y[r];
        if (lane < 32) scR[slot][128 + lane] = z[r];
      }
      *reinterpret_cast<int4*>(&nbrRing[((pc & 3) << 8) + 4 * lane]) = nb4;
      if (lane == 0)
        __hip_atomic_store(&prod_done, pc + 1, __ATOMIC_RELEASE, WG_SCOPE);
    }
    return;
  }

  // ================= consumer wave =================
  while (__hip_atomic_load(&prod_done, __ATOMIC_ACQUIRE, WG_SCOPE) < 2) {}

  int aC[5], bC[5];        // current candidates (A = odd rows, B = even)
  unsigned aB[5], bB[5];   // current ban-mask words per candidate
  bool aH, bH;             // current hf flags
  int PC_aC[5], PC_bC[5];  // pending candidates (rows v+2 at consume time)
  int aPN, bPN;            // pending nbr regs (row whose mask builds next)

  // --- prologue ---
  {
    // A.cur = row 1 (mask complete: colors[0] present)
#pragma unroll
    for (int j = 0; j < 5; ++j) aC[j] = scR16[320 + 64 * j + lane];
    const int nb1 = nbrRing[32 + ln32];
    bbuf[1][lane & 15] = 0u;
    aH = false;
    int cg = colors[nb1];
    if (cg >= 0) atomicOr(&bbuf[1][cg >> 5], 1u << (cg & 31));
#pragma unroll
    for (int j = 0; j < 5; ++j) aB[j] = bbuf[1][aC[j] >> 5];

    // B.cur = row 2 (missing colors[1] -> hf fix vs chosen_1)
#pragma unroll
    for (int j = 0; j < 5; ++j) bC[j] = scR16[2 * 320 + 64 * j + lane];
    const int nb2 = nbrRing[64 + ln32];
    bbuf[0][lane & 15] = 0u;
    bH = (__ballot(nb2 == 1) != 0ULL);
    cg = colors[nb2];
    if (cg >= 0) atomicOr(&bbuf[0][cg >> 5], 1u << (cg & 31));
#pragma unroll
    for (int j = 0; j < 5; ++j) bB[j] = bbuf[0][bC[j] >> 5];

    // A.pending = row 3 candidates + nbr (used by iter v=1's maskbuild)
#pragma unroll
    for (int j = 0; j < 5; ++j) PC_aC[j] = scR16[3 * 320 + 64 * j + lane];
    aPN = nbrRing[96 + ln32];
    bPN = 0;  // written by iter v=1's candload before first use (iter v=2)
  }

  int chosen_prev = 0;
  int n_used = 1;

  for (int v = 1; v + 1 < NV; v += 2) {
    HALF_STEP(v,     aC, aB, aH, aPN, PC_bC, bPN, true)   // odd row
    HALF_STEP(v + 1, bC, bB, bH, bPN, PC_aC, aPN, false)  // even row
  }
  // tail v = 8191 (parity A): sync + critical only
  {
    const int v_ = NV - 1;
    if (lane == 0)
      __hip_atomic_store(&cons_done, (v_ + 1) >> 3, __ATOMIC_RELEASE, WG_SCOPE);
    const int nu_ = n_used, fx_ = chosen_prev;
    bool al0 = (!((aB[0] >> (aC[0] & 31)) & 1u)) &&
               (aC[0] < nu_ || aC[0] == 256) && !(aH && aC[0] == fx_);
    bool al1 = (!((aB[1] >> (aC[1] & 31)) & 1u)) &&
               (aC[1] < nu_ || aC[1] == 256) && !(aH && aC[1] == fx_);
    bool al2 = (!((aB[2] >> (aC[2] & 31)) & 1u)) &&
               (aC[2] < nu_ || aC[2] == 256) && !(aH && aC[2] == fx_);
    bool al3 = (!((aB[3] >> (aC[3] & 31)) & 1u)) &&
               (aC[3] < nu_ || aC[3] == 256) && !(aH && aC[3] == fx_);
    bool al4 = (!((aB[4] >> (aC[4] & 31)) & 1u)) &&
               (aC[4] < nu_ || aC[4] == 256) && !(aH && aC[4] == fx_);
    int raw = 256;
    {
      uint64_t b_ = __ballot(al0);
      if (b_) raw = __builtin_amdgcn_readlane(aC[0], (int)__builtin_ctzll(b_));
      else if ((b_ = __ballot(al1)))
        raw = __builtin_amdgcn_readlane(aC[1], (int)__builtin_ctzll(b_));
      else if ((b_ = __ballot(al2)))
        raw = __builtin_amdgcn_readlane(aC[2], (int)__builtin_ctzll(b_));
      else if ((b_ = __ballot(al3)))
        raw = __builtin_amdgcn_readlane(aC[3], (int)__builtin_ctzll(b_));
      else if ((b_ = __ballot(al4)))
        raw = __builtin_amdgcn_readlane(aC[4], (int)__builtin_ctzll(b_));
    }
    const bool isnew_ = (raw == 256);
    const int chosen_ = isnew_ ? nu_ : raw;
    if (isnew_) ++n_used;
    if (lane == 0) {
      colors[v_] = chosen_;
      rawnu[v_] = (unsigned)raw | ((unsigned)nu_ << 16);
    }
  }

  for (int i = lane; i < NV; i += 64) out[i] = (float)colors[i];
}

// ---------------------------------------------------------------------------
// K4: parallel logp recomputation (unchanged).
// ---------------------------------------------------------------------------
__global__ __launch_bounds__(256) void logp_part(
    const float* __restrict__ outF, const int* __restrict__ nbrG,
    const float* __restrict__ er, const unsigned* __restrict__ rawnu,
    double* __restrict__ partd)
{
  __shared__ unsigned bb[4][16];
  const int t = threadIdx.x;
  const int w = t >> 6;
  const int lane = t & 63;
  const int ln32 = lane & 31;
  const int b = blockIdx.x;

  double a = 0.0;
  for (int i = 0; i < 32; ++i) {
    const int v = b * 128 + w * 32 + i;
    if (v == 0) continue;
    const unsigned val = rawnu[v];
    const int raw = (int)(val & 0xFFFFu);
    const int nu  = (int)(val >> 16);

    bb[w][lane & 15] = 0u;
    const int u = nbrG[(size_t)v * DEG + ln32];
    const int cu = (u < v) ? (int)outF[u] : -1;
    if (cu >= 0) atomicOr(&bb[w][cu >> 5], 1u << (cu & 31));
    unsigned bwp[4];
#pragma unroll
    for (int j = 0; j < 4; ++j) bwp[j] = bb[w][(lane >> 5) + 2 * j];
    const unsigned bw8 = bb[w][8];

    const size_t base = (size_t)v * RSTRIDE;
    bool mk[4];
    float e[4];
#pragma unroll
    for (int j = 0; j < 4; ++j) {
      const int c = lane + 64 * j;
      mk[j] = (((bwp[j] >> ln32) & 1u) != 0u) || (c >= nu);
      e[j] = mk[j] ? 0.f : er[base + c];
    }
    const bool mkX = ((bw8 & 1u) != 0u);
    const float eX = er[base + 256];
    const float e4 = (!mkX && lane == 0) ? eX : 0.f;

    float S = ((e[0] + e[1]) + (e[2] + e[3])) + e4;
    SRED(0x111) SRED(0x112) SRED(0x114) SRED(0x118) SRED(0x142) SRED(0x143)
    const float Sall = __int_as_float(
        __builtin_amdgcn_readlane(__float_as_int(S), 63));

    const bool isnew = (raw == 256);
    const int jsel  = isnew ? 4 : (raw >> 6);
    const int owner = isnew ? 0 : (raw & 63);
    const float cand = (jsel == 0) ? e[0] : (jsel == 1) ? e[1]
                     : (jsel == 2) ? e[2] : (jsel == 3) ? e[3] : e4;
    const float praw = __int_as_float(
        __builtin_amdgcn_readlane(__float_as_int(cand), owner));

    const float p = praw / Sall;
    a += (double)(logf(p + 1e-8f) - logf(1e-8f));
  }
  if (lane == 0) partd[b * 4 + w] = a;
}

__global__ __launch_bounds__(64) void finalize(
    const double* __restrict__ partd, const unsigned* __restrict__ rawnu,
    const float* __restrict__ baseline, float* __restrict__ out)
{
  if (threadIdx.x == 0) {
    double lp = 0.0;
    for (int i = 0; i < 256; ++i) lp += partd[i];
    const unsigned val = rawnu[NV - 1];
    const unsigned nf = (val >> 16) + (((val & 0xFFFFu) == 256u) ? 1u : 0u);
    out[NV] = ((float)nf - baseline[0]) * (float)lp / 8192.0f;
  }
}

// ---------------------------------------------------------------------------
extern "C" void kernel_launch(void* const* d_in, const int* in_sizes, int n_in,
                              void* d_out, int out_size, void* d_ws, size_t ws_size,
                              hipStream_t stream) {
  const float* emb      = (const float*)d_in[0];
  const int*   nbr      = (const int*)d_in[1];
  const float* W1       = (const float*)d_in[2];
  const float* b1       = (const float*)d_in[3];
  const float* W2       = (const float*)d_in[4];
  const float* b2       = (const float*)d_in[5];
  const float* W3       = (const float*)d_in[6];
  const float* b3       = (const float*)d_in[7];
  const float* baseline = (const float*)d_in[8];
  float* out = (float*)d_out;

  char* ws = (char*)d_ws;
  float* g     = (float*)ws;                               // 2 KB
  float* plbuf = (float*)(ws + 2048);                      // 8192*260*4 B
  float* erbuf = (float*)(ws + 2048 + NV * RSTRIDE * 4);   // 8192*260*4 B
  float* part  = erbuf;  // alias: consumed by colmean_fin BEFORE mlp3h writes er
  // rawnu/partd alias long-dead head of plbuf (consumed before writes land):
  unsigned* rawnu = (unsigned*)(ws + 2048);                // 32 KB
  double*   partd = (double*)(ws + 2048 + 65536);          // 2 KB

  colmean_part<<<64, 256, 0, stream>>>(emb, part);
  colmean_fin<<<1, 256, 0, stream>>>(part, g);
  mlp3h<<<NV / TV, 256, 0, stream>>>(emb, g, W1, b1, W2, b2, W3, b3, plbuf, erbuf);
  sortrows<<<NV / 4, 256, 0, stream>>>(plbuf);
  scan6<<<1, 128, 0, stream>>>(nbr, (const uint32_t*)plbuf, rawnu, out);
  logp_part<<<64, 256, 0, stream>>>((const float*)out, nbr, erbuf, rawnu, partd);
  finalize<<<1, 64, 0, stream>>>(partd, rawnu, baseline, out);
}